// Round 10
// baseline (411.390 us; speedup 1.0000x reference)
//
#include <hip/hip_runtime.h>
#include <hip/hip_bf16.h>

typedef __bf16 bf16x8 __attribute__((ext_vector_type(8)));
typedef float  f32x4  __attribute__((ext_vector_type(4)));

__device__ __forceinline__ float blo(unsigned v) { return __uint_as_float(v << 16); }
__device__ __forceinline__ float bhi(unsigned v) { return __uint_as_float(v & 0xffff0000u); }
// round-to-nearest-even f32 -> bf16 (finite inputs)
__device__ __forceinline__ unsigned short f2bf(float f) {
    unsigned u = __float_as_uint(f);
    u += 0x7fffu + ((u >> 16) & 1u);
    return (unsigned short)(u >> 16);
}
// tanh-form gelu via fast exp; |err| ~3e-4 (invisible vs bf16 storage rounding)
__device__ __forceinline__ float gelu_f(float x) {
    float t = 0.7978845608028654f * (x + 0.044715f * x * x * x);
    float e = __expf(2.0f * t);
    float th = 1.0f - 2.0f / (1.0f + e);
    return 0.5f * x * (1.0f + th);
}

// ---------------- preprocessing ----------------

__global__ void degree_kernel(const int* __restrict__ dst, int* __restrict__ deg, int E) {
    int e = blockIdx.x * blockDim.x + threadIdx.x;
    if (e < E) atomicAdd(&deg[dst[e]], 1);
}

__global__ void chunk_sum_kernel(const int* __restrict__ deg, int* __restrict__ bsum, int n) {
    int i = blockIdx.x * 1024 + threadIdx.x;
    int v = (i < n) ? deg[i] : 0;
#pragma unroll
    for (int m = 1; m < 64; m <<= 1) v += __shfl_xor(v, m, 64);
    __shared__ int ws[16];
    int wave = threadIdx.x >> 6, lane = threadIdx.x & 63;
    if (lane == 0) ws[wave] = v;
    __syncthreads();
    if (threadIdx.x == 0) {
        int s = 0;
#pragma unroll
        for (int k = 0; k < 16; ++k) s += ws[k];
        bsum[blockIdx.x] = s;
    }
}

__global__ void chunk_scan_kernel(const int* __restrict__ bsum, int* __restrict__ bbase,
                                  int nb, int* __restrict__ offsets, int n, int E) {
    int lane = threadIdx.x;  // 64
    int v = (lane < nb) ? bsum[lane] : 0;
    int s = v;
#pragma unroll
    for (int m = 1; m < 64; m <<= 1) {
        int t = __shfl_up(s, m, 64);
        if (lane >= m) s += t;
    }
    if (lane < nb) bbase[lane] = s - v;
    if (lane == 0) offsets[n] = E;
}

__global__ void scan_apply_kernel(const int* __restrict__ deg, const int* __restrict__ bbase,
                                  int* __restrict__ offsets, int* __restrict__ cursor, int n) {
    int i = blockIdx.x * 1024 + threadIdx.x;
    int lane = threadIdx.x & 63, wave = threadIdx.x >> 6;
    int v = (i < n) ? deg[i] : 0;
    int s = v;
#pragma unroll
    for (int m = 1; m < 64; m <<= 1) {
        int t = __shfl_up(s, m, 64);
        if (lane >= m) s += t;
    }
    __shared__ int ws[16];
    if (lane == 63) ws[wave] = s;
    __syncthreads();
    if (wave == 0 && lane < 16) {
        int wv = ws[lane];
        int ss = wv;
#pragma unroll
        for (int m = 1; m < 16; m <<= 1) {
            int t = __shfl_up(ss, m, 64);
            if (lane >= m) ss += t;
        }
        ws[lane] = ss - wv;
    }
    __syncthreads();
    int excl = (s - v) + ws[wave] + bbase[blockIdx.x];
    if (i < n) { offsets[i] = excl; cursor[i] = excl; }
}

__global__ void scatter_kernel(const int* __restrict__ src, const int* __restrict__ dst,
                               int* __restrict__ cursor, int* __restrict__ sorted_src, int E) {
    int e = blockIdx.x * blockDim.x + threadIdx.x;
    if (e < E) {
        int d = dst[e];
        int pos = atomicAdd(&cursor[d], 1);
        sorted_src[pos] = src[e];
    }
}

__global__ void bounds_kernel(const int* __restrict__ batch, int* __restrict__ gstart,
                              int N, int G) {
    int g = blockIdx.x * blockDim.x + threadIdx.x;
    if (g <= G) {
        int lo = 0, hi = N;
        while (lo < hi) {
            int mid = (lo + hi) >> 1;
            if (batch[mid] < g) lo = mid + 1; else hi = mid;
        }
        gstart[g] = lo;
    }
}

__global__ void cvt_kernel(const float4* __restrict__ in, ushort4* __restrict__ out, int n4) {
    int i = blockIdx.x * blockDim.x + threadIdx.x;
    if (i < n4) {
        float4 f = in[i];
        ushort4 o; o.x = f2bf(f.x); o.y = f2bf(f.y); o.z = f2bf(f.z); o.w = f2bf(f.w);
        out[i] = o;
    }
}

// all 4 layers' Wcat in one launch: idx = l*32768 + j*256 + k
__global__ void build_wcat_all(const float* __restrict__ Wr0, const float* __restrict__ Wn0,
                               const float* __restrict__ Wr1, const float* __restrict__ Wn1,
                               const float* __restrict__ Wr2, const float* __restrict__ Wn2,
                               const float* __restrict__ Wr3, const float* __restrict__ Wn3,
                               __hip_bfloat16* __restrict__ wcat) {  // [4][128][256]
    int idx = blockIdx.x * blockDim.x + threadIdx.x;
    if (idx >= 4 * 128 * 256) return;
    int l = idx >> 15;
    int j = (idx >> 8) & 127, k = idx & 255;
    const float* Wr = (l == 0) ? Wr0 : (l == 1) ? Wr1 : (l == 2) ? Wr2 : Wr3;
    const float* Wn = (l == 0) ? Wn0 : (l == 1) ? Wn1 : (l == 2) ? Wn2 : Wn3;
    float v = (k < 128) ? Wr[j * 128 + k] : Wn[j * 128 + (k - 128)];
    wcat[idx] = __float2bfloat16(v);
}

// ---------------- fused per-layer kernel ----------------
// Block = 8 waves (512 thr) owns 32 output rows (was 64): grid 1250 blocks =
// ~4.9 blocks/CU -> ~2x waves chip-wide vs round 9 (latency-bound gather fix).
// Phase 1: each wave aggregates 4 nodes into LDS (264B-padded rows).
// Phase 2: wave = colgroup (16 cols) over 32 rows; B-frags register-resident.
#define LDS_STRIDE 264
__global__ __launch_bounds__(512, 4)
void layer_kernel(const __hip_bfloat16* __restrict__ h,
                  const int* __restrict__ offsets,
                  const int* __restrict__ sorted_src,
                  const __hip_bfloat16* __restrict__ Wcat,  // [128][256]
                  const float* __restrict__ bias,           // [128]
                  __hip_bfloat16* __restrict__ out, int N) {
    __shared__ char lds[32 * LDS_STRIDE];
    int wave = threadIdx.x >> 6;
    int lane = threadIdx.x & 63;
    int row0 = blockIdx.x * 32;
    int half = lane >> 5, fl = lane & 31;
    const uint2* hu = (const uint2*)h;

    // ---- phase 1: aggregate 4 nodes per wave ----
#pragma unroll 1
    for (int i = 0; i < 4; ++i) {
        int lr = wave * 4 + i;
        int node = row0 + lr;
        if (node < N && lr < 32) {
            int s = offsets[node], e = offsets[node + 1];
            f32x4 A0 = {0,0,0,0}, A1 = {0,0,0,0}, A2 = {0,0,0,0}, A3 = {0,0,0,0};
            int t = s;
            for (; t + 8 <= e; t += 8) {
                int j0 = sorted_src[t + half];
                int j1 = sorted_src[t + 2 + half];
                int j2 = sorted_src[t + 4 + half];
                int j3 = sorted_src[t + 6 + half];
                uint2 v0 = hu[(size_t)j0 * 32 + fl];
                uint2 v1 = hu[(size_t)j1 * 32 + fl];
                uint2 v2 = hu[(size_t)j2 * 32 + fl];
                uint2 v3 = hu[(size_t)j3 * 32 + fl];
                A0[0] += blo(v0.x); A0[1] += bhi(v0.x); A0[2] += blo(v0.y); A0[3] += bhi(v0.y);
                A1[0] += blo(v1.x); A1[1] += bhi(v1.x); A1[2] += blo(v1.y); A1[3] += bhi(v1.y);
                A2[0] += blo(v2.x); A2[1] += bhi(v2.x); A2[2] += blo(v2.y); A2[3] += bhi(v2.y);
                A3[0] += blo(v3.x); A3[1] += bhi(v3.x); A3[2] += blo(v3.y); A3[3] += bhi(v3.y);
            }
            if (t + 4 <= e) {
                int j0 = sorted_src[t + half];
                int j1 = sorted_src[t + 2 + half];
                uint2 v0 = hu[(size_t)j0 * 32 + fl];
                uint2 v1 = hu[(size_t)j1 * 32 + fl];
                A0[0] += blo(v0.x); A0[1] += bhi(v0.x); A0[2] += blo(v0.y); A0[3] += bhi(v0.y);
                A1[0] += blo(v1.x); A1[1] += bhi(v1.x); A1[2] += blo(v1.y); A1[3] += bhi(v1.y);
                t += 4;
            }
            if (t + 2 <= e) {
                int j0 = sorted_src[t + half];
                uint2 v0 = hu[(size_t)j0 * 32 + fl];
                A0[0] += blo(v0.x); A0[1] += bhi(v0.x); A0[2] += blo(v0.y); A0[3] += bhi(v0.y);
                t += 2;
            }
            if (t < e && half == 0) {   // odd tail: lo-half only
                int j = sorted_src[t];
                uint2 v = hu[(size_t)j * 32 + fl];
                A1[0] += blo(v.x); A1[1] += bhi(v.x); A1[2] += blo(v.y); A1[3] += bhi(v.y);
            }
            float q0 = (A0[0] + A1[0]) + (A2[0] + A3[0]); q0 += __shfl_xor(q0, 32, 64);
            float q1 = (A0[1] + A1[1]) + (A2[1] + A3[1]); q1 += __shfl_xor(q1, 32, 64);
            float q2 = (A0[2] + A1[2]) + (A2[2] + A3[2]); q2 += __shfl_xor(q2, 32, 64);
            float q3 = (A0[3] + A1[3]) + (A2[3] + A3[3]); q3 += __shfl_xor(q3, 32, 64);
            if (half == 0) {
                ushort4 o; o.x = f2bf(q0); o.y = f2bf(q1); o.z = f2bf(q2); o.w = f2bf(q3);
                *reinterpret_cast<ushort4*>(&lds[lr * LDS_STRIDE + fl * 8]) = o;
            }
        }
    }
    __syncthreads();

    // ---- phase 2: gemm (32 rows x 16 cols per wave) ----
    int la  = lane & 15;
    int keg = lane >> 4;
    int ke0 = keg * 8;
    int col = wave * 16 + la;

    bf16x8 b[8];
#pragma unroll
    for (int ks = 0; ks < 8; ++ks)
        b[ks] = *reinterpret_cast<const bf16x8*>(&Wcat[(size_t)col * 256 + ks * 32 + ke0]);
    float bv = bias[col];

    f32x4 acc[2];
#pragma unroll
    for (int m = 0; m < 2; ++m) {
        int r = row0 + m * 16 + la;
        if (r >= N) r = N - 1;
        const __hip_bfloat16* hr = &h[(size_t)r * 128];
        bf16x8 a[8];
#pragma unroll
        for (int ks = 0; ks < 4; ++ks)
            a[ks] = *reinterpret_cast<const bf16x8*>(&hr[ks * 32 + ke0]);
#pragma unroll
        for (int ks = 0; ks < 4; ++ks)
            a[ks + 4] = *reinterpret_cast<const bf16x8*>(
                &lds[(m * 16 + la) * LDS_STRIDE + ks * 64 + keg * 16]);
        f32x4 c = {0, 0, 0, 0};
#pragma unroll
        for (int ks = 0; ks < 8; ++ks)
            c = __builtin_amdgcn_mfma_f32_16x16x32_bf16(a[ks], b[ks], c, 0, 0, 0);
        acc[m] = c;
    }

    int r0 = row0 + (lane >> 4) * 4;
#pragma unroll
    for (int m = 0; m < 2; ++m) {
#pragma unroll
        for (int j = 0; j < 4; ++j) {
            int r = r0 + m * 16 + j;
            if (r < N)
                out[(size_t)r * 128 + col] = __float2bfloat16(gelu_f(acc[m][j] + bv));
        }
    }
}

// ---------------- pooling ----------------

__global__ void pool_partial(const __hip_bfloat16* __restrict__ h,
                             const int* __restrict__ batch,
                             const float* __restrict__ Wout,
                             float* __restrict__ outsum, int N) {
    int wid = blockIdx.x * 4 + (threadIdx.x >> 6);
    int lane = threadIdx.x & 63;
    int i0 = wid * 16;
    if (i0 >= N) return;
    int half = lane >> 5, fl = lane & 31;
    const uint2* hu = (const uint2*)h;
    float w0 = Wout[4 * fl], w1 = Wout[4 * fl + 1];
    float w2 = Wout[4 * fl + 2], w3 = Wout[4 * fl + 3];
    float dot = 0.f;
    int cur = -1;
#pragma unroll
    for (int t = 0; t < 8; ++t) {
        int i = i0 + 2 * t + half;
        if (i < N) {
            int g = batch[i];
            uint2 v = hu[(size_t)i * 32 + fl];
            float d = blo(v.x) * w0 + bhi(v.x) * w1 + blo(v.y) * w2 + bhi(v.y) * w3;
            if (g != cur) {
                if (cur >= 0) {
                    float r = dot;
#pragma unroll
                    for (int m = 16; m >= 1; m >>= 1) r += __shfl_xor(r, m, 64);
                    if (fl == 0) atomicAdd(&outsum[cur], r);
                }
                cur = g; dot = d;
            } else {
                dot += d;
            }
        }
    }
    if (cur >= 0) {
        float r = dot;
#pragma unroll
        for (int m = 16; m >= 1; m >>= 1) r += __shfl_xor(r, m, 64);
        if (fl == 0) atomicAdd(&outsum[cur], r);
    }
}

__global__ void pool_finish(const float* __restrict__ outsum,
                            const int* __restrict__ gstart,
                            const float* __restrict__ bout,
                            float* __restrict__ out, int G) {
    int g = blockIdx.x * blockDim.x + threadIdx.x;
    if (g < G) {
        float cnt = (float)(gstart[g + 1] - gstart[g]);
        out[g] = outsum[g] / fmaxf(cnt, 1.0f) + bout[0];
    }
}

// ---------------- launch ----------------

extern "C" void kernel_launch(void* const* d_in, const int* in_sizes, int n_in,
                              void* d_out, int out_size, void* d_ws, size_t ws_size,
                              hipStream_t stream) {
    const float* x          = (const float*)d_in[0];
    const int*   edge_index = (const int*)d_in[1];
    const int*   batch      = (const int*)d_in[2];
    const float* Wroot[4] = {(const float*)d_in[3], (const float*)d_in[6],
                             (const float*)d_in[9], (const float*)d_in[12]};
    const float* Wrel[4]  = {(const float*)d_in[4], (const float*)d_in[7],
                             (const float*)d_in[10], (const float*)d_in[13]};
    const float* bias[4]  = {(const float*)d_in[5], (const float*)d_in[8],
                             (const float*)d_in[11], (const float*)d_in[14]};
    const float* Wout = (const float*)d_in[15];
    const float* bout = (const float*)d_in[16];
    float* out = (float*)d_out;

    const int N = in_sizes[2];       // 40000
    const int E = in_sizes[1] / 2;   // 640000
    const int G = 128;
    const int* src = edge_index;
    const int* dst = edge_index + E;

    char* ws = (char*)d_ws;
    size_t o = 0;
    auto alloc = [&](size_t bytes) { void* p = ws + o; o += (bytes + 255) & ~(size_t)255; return p; };

    __hip_bfloat16* hx   = (__hip_bfloat16*)alloc((size_t)N * 128 * 2);
    __hip_bfloat16* hb0  = (__hip_bfloat16*)alloc((size_t)N * 128 * 2);
    __hip_bfloat16* hb1  = (__hip_bfloat16*)alloc((size_t)N * 128 * 2);
    __hip_bfloat16* wcat = (__hip_bfloat16*)alloc((size_t)4 * 128 * 256 * 2);
    int* deg     = (int*)alloc((size_t)N * 4);
    int* offsets = (int*)alloc((size_t)(N + 1) * 4);
    int* cursor  = (int*)alloc((size_t)N * 4);
    int* sorted  = (int*)alloc((size_t)E * 4);
    int* gstart  = (int*)alloc((size_t)(G + 1) * 4);
    int* bsum    = (int*)alloc(64 * 4);
    int* bbase   = (int*)alloc(64 * 4);
    float* outsum = (float*)alloc((size_t)G * 4);

    const int nb = (N + 1023) / 1024;   // 40 (<=64 required by chunk_scan)

    // CSR build (reused by all 4 layers)
    hipMemsetAsync(deg, 0, (size_t)N * 4, stream);
    degree_kernel<<<(E + 255) / 256, 256, 0, stream>>>(dst, deg, E);
    chunk_sum_kernel<<<nb, 1024, 0, stream>>>(deg, bsum, N);
    chunk_scan_kernel<<<1, 64, 0, stream>>>(bsum, bbase, nb, offsets, N, E);
    scan_apply_kernel<<<nb, 1024, 0, stream>>>(deg, bbase, offsets, cursor, N);
    scatter_kernel<<<(E + 255) / 256, 256, 0, stream>>>(src, dst, cursor, sorted, E);
    bounds_kernel<<<1, 256, 0, stream>>>(batch, gstart, N, G);

    // input & weight conversion to bf16
    cvt_kernel<<<(N * 128 / 4 + 255) / 256, 256, 0, stream>>>(
        (const float4*)x, (ushort4*)hx, N * 128 / 4);
    build_wcat_all<<<(4 * 128 * 256 + 255) / 256, 256, 0, stream>>>(
        Wroot[0], Wrel[0], Wroot[1], Wrel[1], Wroot[2], Wrel[2], Wroot[3], Wrel[3], wcat);

    // 4 fused GraphConv + gelu layers
    __hip_bfloat16* hin = hx;
    __hip_bfloat16* houts[4] = {hb0, hb1, hb0, hb1};
    for (int l = 0; l < 4; ++l) {
        layer_kernel<<<(N + 31) / 32, 512, 0, stream>>>(
            hin, offsets, sorted, wcat + (size_t)l * 128 * 256, bias[l], houts[l], N);
        hin = houts[l];
    }

    // fused mean pool + output head
    hipMemsetAsync(outsum, 0, (size_t)G * 4, stream);
    pool_partial<<<((N + 15) / 16 + 3) / 4, 256, 0, stream>>>(hin, batch, Wout, outsum, N);
    pool_finish<<<1, 128, 0, stream>>>(outsum, gstart, bout, out, G);
}